// Round 1
// baseline (662.414 us; speedup 1.0000x reference)
//
#include <hip/hip_runtime.h>

#define DIMK 512
#define NHEADS 8
#define DH 64
#define NBATCH 16
#define QLEN 512
#define KVLEN 1024
#define NQ (NBATCH*QLEN)     /* 8192  */
#define NKV (NBATCH*KVLEN)   /* 16384 */

// ---------------------------------------------------------------------------
// Kernel 1: per-row LayerNorm stats (mean, rstd). One wave per row.
// ---------------------------------------------------------------------------
__global__ __launch_bounds__(256) void ln_stats_kernel(const float* __restrict__ x,
                                                       float* __restrict__ stats,
                                                       int nrows) {
    int row  = blockIdx.x * 4 + (threadIdx.x >> 6);
    int lane = threadIdx.x & 63;
    if (row >= nrows) return;
    const float4* xr = reinterpret_cast<const float4*>(x + (size_t)row * DIMK);
    float4 v0 = xr[lane * 2];
    float4 v1 = xr[lane * 2 + 1];
    float s  = v0.x + v0.y + v0.z + v0.w + v1.x + v1.y + v1.z + v1.w;
    float sq = v0.x*v0.x + v0.y*v0.y + v0.z*v0.z + v0.w*v0.w
             + v1.x*v1.x + v1.y*v1.y + v1.z*v1.z + v1.w*v1.w;
    #pragma unroll
    for (int off = 32; off; off >>= 1) {
        s  += __shfl_xor(s, off);
        sq += __shfl_xor(sq, off);
    }
    if (lane == 0) {
        float mu  = s * (1.0f / DIMK);
        float var = sq * (1.0f / DIMK) - mu * mu;
        float2 st;
        st.x = mu;
        st.y = rsqrtf(var + 1e-5f);
        reinterpret_cast<float2*>(stats)[row] = st;
    }
}

// ---------------------------------------------------------------------------
// Kernel 2: tiled f32 GEMM, 128x128 block tile, BK=16, 256 threads, 8x8 micro.
// MODE 0: C = rope(LN(A) @ W, freqs)            (q projection)
// MODE 1: same, N=1024, rope on all cols        (kv projection; k and v both roped)
// MODE 2: C = A @ W + bias                      (output projection)
// ---------------------------------------------------------------------------
template<int MODE>
__global__ __launch_bounds__(256) void gemm_kernel(
    const float* __restrict__ A, const float* __restrict__ Bw, float* __restrict__ C,
    const float* __restrict__ stats, const float* __restrict__ gamma,
    const float* __restrict__ beta, const float* __restrict__ freqs,
    const float* __restrict__ bias, int M, int N)
{
    __shared__ float As[16][132];   // [k][row], padded: write 2-way, read free
    __shared__ float Bs[16][128];   // [k][col]
    const int t  = threadIdx.x;
    const int tx = t & 15;          // col group
    const int ty = t >> 4;          // row group
    const int col0 = blockIdx.x * 128;
    const int row0 = blockIdx.y * 128;

    float acc[8][8];
    #pragma unroll
    for (int j = 0; j < 8; ++j)
        #pragma unroll
        for (int i = 0; i < 8; ++i) acc[j][i] = 0.f;

    for (int k0 = 0; k0 < DIMK; k0 += 16) {
        // ---- A tile (optionally fused LayerNorm) ----
        #pragma unroll
        for (int r = 0; r < 8; ++r) {
            int idx = r * 256 + t;
            int ar = idx >> 4, ak = idx & 15;
            float a = A[(size_t)(row0 + ar) * DIMK + (k0 + ak)];
            if (MODE != 2) {
                float2 st = reinterpret_cast<const float2*>(stats)[row0 + ar];
                a = (a - st.x) * st.y * gamma[k0 + ak] + beta[k0 + ak];
            }
            As[ak][ar] = a;
        }
        // ---- B tile ----
        #pragma unroll
        for (int r = 0; r < 8; ++r) {
            int idx = r * 256 + t;
            int bk = idx >> 7, bc = idx & 127;
            Bs[bk][bc] = Bw[(size_t)(k0 + bk) * N + (col0 + bc)];
        }
        __syncthreads();
        // ---- inner product ----
        #pragma unroll
        for (int kk = 0; kk < 16; ++kk) {
            float4 a0 = *reinterpret_cast<const float4*>(&As[kk][ty * 4]);
            float4 a1 = *reinterpret_cast<const float4*>(&As[kk][64 + ty * 4]);
            float4 b0 = *reinterpret_cast<const float4*>(&Bs[kk][tx * 4]);
            float4 b1 = *reinterpret_cast<const float4*>(&Bs[kk][64 + tx * 4]);
            float av[8] = {a0.x, a0.y, a0.z, a0.w, a1.x, a1.y, a1.z, a1.w};
            float bv[8] = {b0.x, b0.y, b0.z, b0.w, b1.x, b1.y, b1.z, b1.w};
            #pragma unroll
            for (int j = 0; j < 8; ++j)
                #pragma unroll
                for (int i = 0; i < 8; ++i)
                    acc[j][i] = fmaf(av[j], bv[i], acc[j][i]);
        }
        __syncthreads();
    }

    // ---- epilogue ----
    #pragma unroll
    for (int jc = 0; jc < 2; ++jc) {
        #pragma unroll
        for (int j = 0; j < 4; ++j) {
            int gr = row0 + jc * 64 + ty * 4 + j;
            #pragma unroll
            for (int ic = 0; ic < 2; ++ic) {
                int gc = col0 + ic * 64 + tx * 4;
                float x0 = acc[jc * 4 + j][ic * 4 + 0];
                float y0 = acc[jc * 4 + j][ic * 4 + 1];
                float x1 = acc[jc * 4 + j][ic * 4 + 2];
                float y1 = acc[jc * 4 + j][ic * 4 + 3];
                float4 rr;
                if (MODE == 2) {
                    rr.x = x0 + bias[gc + 0];
                    rr.y = y0 + bias[gc + 1];
                    rr.z = x1 + bias[gc + 2];
                    rr.w = y1 + bias[gc + 3];
                } else {
                    int d = gc & 63;  // even (gc multiple of 4)
                    const float* fr = freqs + (size_t)gr * DH;
                    float f0 = fr[d], f1 = fr[d + 2];
                    float s0, c0, s1, c1;
                    sincosf(f0, &s0, &c0);
                    sincosf(f1, &s1, &c1);
                    // rope: (x,y) -> (x c - y s, y c + x s)
                    rr.x = x0 * c0 - y0 * s0;
                    rr.y = y0 * c0 + x0 * s0;
                    rr.z = x1 * c1 - y1 * s1;
                    rr.w = y1 * c1 + x1 * s1;
                }
                *reinterpret_cast<float4*>(&C[(size_t)gr * N + gc]) = rr;
            }
        }
    }
}

// ---------------------------------------------------------------------------
// Kernel 3: flash attention. Block = (64 q-rows, one head, one batch).
// Online softmax over 16 K/V tiles of 64 rows. Inverse-rope epilogue.
// ---------------------------------------------------------------------------
__global__ __launch_bounds__(256) void attn_kernel(
    const float* __restrict__ qb, const float* __restrict__ kvb,
    const float* __restrict__ fq, float* __restrict__ aob)
{
    const int qt = blockIdx.x;   // 0..7
    const int h  = blockIdx.y;   // 0..7
    const int b  = blockIdx.z;   // 0..15
    const int t  = threadIdx.x;
    const int tx = t & 15;       // kr / dh group
    const int ty = t >> 4;       // qr group

    __shared__ float Qs[64][68];   // [d][qr]
    __shared__ float Ks[64][68];   // [d][kr]; reused as P[qr][kr]
    __shared__ float Vs[64][68];   // [kr][d]

    const int q_row0 = b * QLEN + qt * 64;

    #pragma unroll
    for (int r = 0; r < 16; ++r) {
        int idx = r * 256 + t;
        int qr = idx >> 6, d = idx & 63;
        Qs[d][qr] = qb[(size_t)(q_row0 + qr) * 512 + h * 64 + d];
    }

    float m[4], l[4], o[4][4];
    #pragma unroll
    for (int j = 0; j < 4; ++j) {
        m[j] = -1e30f; l[j] = 0.f;
        #pragma unroll
        for (int i = 0; i < 4; ++i) o[j][i] = 0.f;
    }
    __syncthreads();

    for (int kt = 0; kt < 16; ++kt) {
        #pragma unroll
        for (int r = 0; r < 16; ++r) {
            int idx = r * 256 + t;
            int kr = idx >> 6, d = idx & 63;
            size_t g = (size_t)(b * KVLEN + kt * 64 + kr) * 1024 + h * 64 + d;
            Ks[d][kr] = kvb[g];
            Vs[kr][d] = kvb[g + 512];
        }
        __syncthreads();

        // S = (Q K^T) * scale ; thread owns 4 qr x 4 kr
        float s[4][4];
        #pragma unroll
        for (int j = 0; j < 4; ++j)
            #pragma unroll
            for (int i = 0; i < 4; ++i) s[j][i] = 0.f;
        #pragma unroll 8
        for (int d = 0; d < 64; ++d) {
            float4 q4 = *reinterpret_cast<const float4*>(&Qs[d][ty * 4]);
            float4 k4 = *reinterpret_cast<const float4*>(&Ks[d][tx * 4]);
            float qv[4] = {q4.x, q4.y, q4.z, q4.w};
            float kv[4] = {k4.x, k4.y, k4.z, k4.w};
            #pragma unroll
            for (int j = 0; j < 4; ++j)
                #pragma unroll
                for (int i = 0; i < 4; ++i)
                    s[j][i] = fmaf(qv[j], kv[i], s[j][i]);
        }
        #pragma unroll
        for (int j = 0; j < 4; ++j)
            #pragma unroll
            for (int i = 0; i < 4; ++i) s[j][i] *= 0.125f;

        // online softmax (row groups of 16 tx lanes, contiguous in wave)
        float p[4][4];
        #pragma unroll
        for (int j = 0; j < 4; ++j) {
            float mx = fmaxf(fmaxf(s[j][0], s[j][1]), fmaxf(s[j][2], s[j][3]));
            mx = fmaxf(mx, __shfl_xor(mx, 1));
            mx = fmaxf(mx, __shfl_xor(mx, 2));
            mx = fmaxf(mx, __shfl_xor(mx, 4));
            mx = fmaxf(mx, __shfl_xor(mx, 8));
            float mn = fmaxf(m[j], mx);
            float al = __expf(m[j] - mn);
            float rs = 0.f;
            #pragma unroll
            for (int i = 0; i < 4; ++i) {
                p[j][i] = __expf(s[j][i] - mn);
                rs += p[j][i];
            }
            rs += __shfl_xor(rs, 1);
            rs += __shfl_xor(rs, 2);
            rs += __shfl_xor(rs, 4);
            rs += __shfl_xor(rs, 8);
            l[j] = l[j] * al + rs;
            m[j] = mn;
            #pragma unroll
            for (int i = 0; i < 4; ++i) o[j][i] *= al;
        }
        __syncthreads();   // done reading Ks as K
        #pragma unroll
        for (int j = 0; j < 4; ++j)
            #pragma unroll
            for (int i = 0; i < 4; ++i)
                Ks[ty * 4 + j][tx * 4 + i] = p[j][i];   // Ks now holds P[qr][kr]
        __syncthreads();

        // O += P @ V ; thread owns 4 qr x 4 dh (dh = 4*tx+i)
        #pragma unroll 4
        for (int kr = 0; kr < 64; ++kr) {
            float4 v4 = *reinterpret_cast<const float4*>(&Vs[kr][tx * 4]);
            #pragma unroll
            for (int j = 0; j < 4; ++j) {
                float pj = Ks[ty * 4 + j][kr];
                o[j][0] = fmaf(pj, v4.x, o[j][0]);
                o[j][1] = fmaf(pj, v4.y, o[j][1]);
                o[j][2] = fmaf(pj, v4.z, o[j][2]);
                o[j][3] = fmaf(pj, v4.w, o[j][3]);
            }
        }
        __syncthreads();   // before next tile overwrites Ks/Vs
    }

    // epilogue: normalize + inverse rope (-fq) + store
    #pragma unroll
    for (int j = 0; j < 4; ++j) {
        int gr = q_row0 + ty * 4 + j;
        float inv = 1.f / l[j];
        const float* fr = fq + (size_t)gr * DH;
        int d0 = tx * 4;
        float f0 = fr[d0], f1 = fr[d0 + 2];
        float s0, c0, s1, c1;
        sincosf(f0, &s0, &c0);
        sincosf(f1, &s1, &c1);
        float x0 = o[j][0] * inv, y0 = o[j][1] * inv;
        float x1 = o[j][2] * inv, y1 = o[j][3] * inv;
        float4 rr;
        // inverse rope: (x,y) -> (x c + y s, y c - x s)
        rr.x = x0 * c0 + y0 * s0;
        rr.y = y0 * c0 - x0 * s0;
        rr.z = x1 * c1 + y1 * s1;
        rr.w = y1 * c1 - x1 * s1;
        *reinterpret_cast<float4*>(&aob[(size_t)gr * 512 + h * 64 + d0]) = rr;
    }
}

// ---------------------------------------------------------------------------
extern "C" void kernel_launch(void* const* d_in, const int* in_sizes, int n_in,
                              void* d_out, int out_size, void* d_ws, size_t ws_size,
                              hipStream_t stream) {
    const float* x_query   = (const float*)d_in[0];
    const float* x_context = (const float*)d_in[1];
    const float* fq        = (const float*)d_in[2];
    const float* fkv       = (const float*)d_in[3];
    const float* ln_q_g    = (const float*)d_in[4];
    const float* ln_q_b    = (const float*)d_in[5];
    const float* ln_c_g    = (const float*)d_in[6];
    const float* ln_c_b    = (const float*)d_in[7];
    const float* Wq        = (const float*)d_in[8];
    const float* Wkv       = (const float*)d_in[9];
    const float* Wout      = (const float*)d_in[10];
    const float* bout      = (const float*)d_in[11];
    float* out = (float*)d_out;

    float* ws      = (float*)d_ws;
    float* stats_q = ws;                          // 8192*2
    float* stats_c = stats_q + (size_t)NQ * 2;    // 16384*2
    float* qb      = stats_c + (size_t)NKV * 2;   // 8192*512
    float* kvb     = qb + (size_t)NQ * 512;       // 16384*1024
    float* aob     = kvb + (size_t)NKV * 1024;    // 8192*512

    ln_stats_kernel<<<NQ / 4, 256, 0, stream>>>(x_query, stats_q, NQ);
    ln_stats_kernel<<<NKV / 4, 256, 0, stream>>>(x_context, stats_c, NKV);

    gemm_kernel<0><<<dim3(4, 64), 256, 0, stream>>>(
        x_query, Wq, qb, stats_q, ln_q_g, ln_q_b, fq, nullptr, NQ, 512);
    gemm_kernel<1><<<dim3(8, 128), 256, 0, stream>>>(
        x_context, Wkv, kvb, stats_c, ln_c_g, ln_c_b, fkv, nullptr, NKV, 1024);

    attn_kernel<<<dim3(8, NHEADS, NBATCH), 256, 0, stream>>>(qb, kvb, fq, aob);

    gemm_kernel<2><<<dim3(4, 64), 256, 0, stream>>>(
        aob, Wout, out, nullptr, nullptr, nullptr, nullptr, bout, NQ, 512);
}

// Round 2
// 598.648 us; speedup vs baseline: 1.1065x; 1.1065x over previous
//
#include <hip/hip_runtime.h>

#define DIMK 512
#define NHEADS 8
#define DH 64
#define NBATCH 16
#define QLEN 512
#define KVLEN 1024
#define NQ (NBATCH*QLEN)     /* 8192  */
#define NKV (NBATCH*KVLEN)   /* 16384 */

typedef __attribute__((ext_vector_type(8))) short bf16x8;
typedef __attribute__((ext_vector_type(4))) float f32x4;
typedef __attribute__((ext_vector_type(8))) unsigned short us8;

__device__ __forceinline__ float bf2f(unsigned short u) {
    return __uint_as_float(((unsigned)u) << 16);
}
__device__ __forceinline__ unsigned short f2bf(float f) {
    unsigned u = __float_as_uint(f);
    return (unsigned short)((u + 0x7fffu + ((u >> 16) & 1u)) >> 16);
}
__device__ __forceinline__ void gl2lds16(const void* g, const void* lds) {
    __builtin_amdgcn_global_load_lds(
        (const __attribute__((address_space(1))) unsigned int*)g,
        (__attribute__((address_space(3))) unsigned int*)lds, 16, 0, 0);
}

// ---------------------------------------------------------------------------
// LN + bf16 cast, one wave per row of 512.
// ---------------------------------------------------------------------------
__global__ __launch_bounds__(256) void ln_cast_kernel(
    const float* __restrict__ x, const float* __restrict__ g,
    const float* __restrict__ bta, unsigned short* __restrict__ out, int nrows)
{
    int row  = blockIdx.x * 4 + (threadIdx.x >> 6);
    int lane = threadIdx.x & 63;
    if (row >= nrows) return;
    const float4* xr = reinterpret_cast<const float4*>(x + (size_t)row * DIMK);
    float4 v0 = xr[lane * 2];
    float4 v1 = xr[lane * 2 + 1];
    float s  = v0.x + v0.y + v0.z + v0.w + v1.x + v1.y + v1.z + v1.w;
    float sq = v0.x*v0.x + v0.y*v0.y + v0.z*v0.z + v0.w*v0.w
             + v1.x*v1.x + v1.y*v1.y + v1.z*v1.z + v1.w*v1.w;
    #pragma unroll
    for (int off = 32; off; off >>= 1) {
        s  += __shfl_xor(s, off);
        sq += __shfl_xor(sq, off);
    }
    float mu   = s * (1.0f / DIMK);
    float rstd = rsqrtf(sq * (1.0f / DIMK) - mu * mu + 1e-5f);
    const float4* g4 = reinterpret_cast<const float4*>(g + lane * 8);
    const float4* b4 = reinterpret_cast<const float4*>(bta + lane * 8);
    float4 g0 = g4[0], g1 = g4[1], b0 = b4[0], b1 = b4[1];
    us8 o;
    o[0] = f2bf((v0.x - mu) * rstd * g0.x + b0.x);
    o[1] = f2bf((v0.y - mu) * rstd * g0.y + b0.y);
    o[2] = f2bf((v0.z - mu) * rstd * g0.z + b0.z);
    o[3] = f2bf((v0.w - mu) * rstd * g0.w + b0.w);
    o[4] = f2bf((v1.x - mu) * rstd * g1.x + b1.x);
    o[5] = f2bf((v1.y - mu) * rstd * g1.y + b1.y);
    o[6] = f2bf((v1.z - mu) * rstd * g1.z + b1.z);
    o[7] = f2bf((v1.w - mu) * rstd * g1.w + b1.w);
    *reinterpret_cast<us8*>(out + (size_t)row * DIMK + lane * 8) = o;
}

// ---------------------------------------------------------------------------
// Weight transpose + bf16 cast (optional lo part). W is [512][N] -> T [N][512].
// ---------------------------------------------------------------------------
__global__ __launch_bounds__(256) void wt_cast_kernel(
    const float* __restrict__ W, unsigned short* __restrict__ Th,
    unsigned short* __restrict__ Tl, int N)
{
    int idx = blockIdx.x * 256 + threadIdx.x;   // n*512 + k
    int n = idx >> 9, k = idx & 511;
    float v = W[(size_t)k * N + n];
    unsigned short h = f2bf(v);
    Th[idx] = h;
    if (Tl) Tl[idx] = f2bf(v - bf2f(h));
}

// ---------------------------------------------------------------------------
// MFMA GEMM: 128x128 tile, BK=32, 4 waves, each 64x64 via 4x4 16x16x32 frags.
// A [M][512] bf16 row-major, B = W^T [N][512] bf16 row-major.
// MODE 0: C = rope(A@W) -> bf16      MODE 1: same, N=1024 (k and v roped)
// MODE 2: C = (Ah+Al)@(Wh+Wl) + bias -> f32 (split bf16, 3 MFMA)
// ---------------------------------------------------------------------------
template<int MODE>
__global__ __launch_bounds__(256) void mm_kernel(
    const unsigned short* __restrict__ Ah, const unsigned short* __restrict__ Al,
    const unsigned short* __restrict__ Bh, const unsigned short* __restrict__ Bl,
    void* __restrict__ Cout, const float* __restrict__ freqs,
    const float* __restrict__ bias, int N)
{
    constexpr bool SPLIT = (MODE == 2);
    __shared__ __align__(16) unsigned short AsH[128 * 32];
    __shared__ __align__(16) unsigned short BsH[128 * 32];
    __shared__ __align__(16) unsigned short AsL[SPLIT ? 128 * 32 : 8];
    __shared__ __align__(16) unsigned short BsL[SPLIT ? 128 * 32 : 8];

    const int t = threadIdx.x;
    const int lane = t & 63, w = t >> 6;
    const int l15 = lane & 15, l4 = lane >> 4;
    const int wr = w >> 1, wc = w & 1;
    const int col0 = blockIdx.x * 128;
    const int row0 = blockIdx.y * 128;
    const int stRow = lane >> 2;          // row within 16-row sub-block
    const int stK   = (lane & 3) * 8;     // element offset within 32-elem row

    f32x4 acc[4][4];
    #pragma unroll
    for (int m = 0; m < 4; ++m)
        #pragma unroll
        for (int n = 0; n < 4; ++n)
            acc[m][n] = (f32x4){0.f, 0.f, 0.f, 0.f};

    for (int k0 = 0; k0 < 512; k0 += 32) {
        constexpr int NI = SPLIT ? 8 : 4;
        #pragma unroll
        for (int j = 0; j < NI; ++j) {
            int id  = w * NI + j;
            int arr = id >> 3;            // 0:AH 1:BH 2:AL 3:BL
            int sub = id & 7;
            int row = sub * 16 + stRow;
            const unsigned short* gsrc;
            unsigned short* ldst;
            if (arr == 0)      { gsrc = Ah + (size_t)(row0 + row) * 512; ldst = AsH; }
            else if (arr == 1) { gsrc = Bh + (size_t)(col0 + row) * 512; ldst = BsH; }
            else if (arr == 2) { gsrc = Al + (size_t)(row0 + row) * 512; ldst = AsL; }
            else               { gsrc = Bl + (size_t)(col0 + row) * 512; ldst = BsL; }
            gl2lds16(gsrc + k0 + stK, ldst + sub * 512);
        }
        __syncthreads();

        bf16x8 fah[4], fbh[4];
        #pragma unroll
        for (int m = 0; m < 4; ++m)
            fah[m] = *reinterpret_cast<const bf16x8*>(&AsH[(wr*64 + m*16 + l15) * 32 + l4*8]);
        #pragma unroll
        for (int n = 0; n < 4; ++n)
            fbh[n] = *reinterpret_cast<const bf16x8*>(&BsH[(wc*64 + n*16 + l15) * 32 + l4*8]);
        if constexpr (SPLIT) {
            bf16x8 fal[4], fbl[4];
            #pragma unroll
            for (int m = 0; m < 4; ++m)
                fal[m] = *reinterpret_cast<const bf16x8*>(&AsL[(wr*64 + m*16 + l15) * 32 + l4*8]);
            #pragma unroll
            for (int n = 0; n < 4; ++n)
                fbl[n] = *reinterpret_cast<const bf16x8*>(&BsL[(wc*64 + n*16 + l15) * 32 + l4*8]);
            #pragma unroll
            for (int m = 0; m < 4; ++m)
                #pragma unroll
                for (int n = 0; n < 4; ++n) {
                    acc[m][n] = __builtin_amdgcn_mfma_f32_16x16x32_bf16(fah[m], fbh[n], acc[m][n], 0, 0, 0);
                    acc[m][n] = __builtin_amdgcn_mfma_f32_16x16x32_bf16(fah[m], fbl[n], acc[m][n], 0, 0, 0);
                    acc[m][n] = __builtin_amdgcn_mfma_f32_16x16x32_bf16(fal[m], fbh[n], acc[m][n], 0, 0, 0);
                }
        } else {
            #pragma unroll
            for (int m = 0; m < 4; ++m)
                #pragma unroll
                for (int n = 0; n < 4; ++n)
                    acc[m][n] = __builtin_amdgcn_mfma_f32_16x16x32_bf16(fah[m], fbh[n], acc[m][n], 0, 0, 0);
        }
        __syncthreads();
    }

    // epilogue: C/D layout col=lane&15, row=(lane>>4)*4+j
    #pragma unroll
    for (int m = 0; m < 4; ++m) {
        #pragma unroll
        for (int n = 0; n < 4; ++n) {
            #pragma unroll
            for (int j = 0; j < 4; ++j) {
                float v = acc[m][n][j];
                int gr = row0 + wr*64 + m*16 + l4*4 + j;
                int gc = col0 + wc*64 + n*16 + l15;
                if constexpr (MODE == 2) {
                    ((float*)Cout)[(size_t)gr * N + gc] = v + bias[gc];
                } else {
                    float pv = __shfl_xor(v, 1);         // partner column of rope pair
                    float f = freqs[(size_t)gr * DH + (gc & 63)];
                    float sn, cs;
                    sincosf(f, &sn, &cs);
                    float nv = (lane & 1) ? fmaf(pv, sn, v * cs)    // odd:  y c + x s
                                          : fmaf(-pv, sn, v * cs);  // even: x c - y s
                    ((unsigned short*)Cout)[(size_t)gr * N + gc] = f2bf(nv);
                }
            }
        }
    }
}

// ---------------------------------------------------------------------------
// Flash attention (f32 compute, bf16 in, split-bf16 out). Unchanged math.
// ---------------------------------------------------------------------------
__global__ __launch_bounds__(256) void attn_kernel(
    const unsigned short* __restrict__ qb, const unsigned short* __restrict__ kvb,
    const float* __restrict__ fq, unsigned short* __restrict__ aobH,
    unsigned short* __restrict__ aobL)
{
    const int qt = blockIdx.x;   // 0..7
    const int h  = blockIdx.y;   // 0..7
    const int b  = blockIdx.z;   // 0..15
    const int t  = threadIdx.x;
    const int tx = t & 15;
    const int ty = t >> 4;

    __shared__ float Qs[64][68];
    __shared__ float Ks[64][68];
    __shared__ float Vs[64][68];

    const int q_row0 = b * QLEN + qt * 64;

    const ushort2* q2 = reinterpret_cast<const ushort2*>(qb + (size_t)q_row0 * 512 + h * 64);
    #pragma unroll
    for (int r = 0; r < 8; ++r) {
        int idx = r * 256 + t;
        int qr = idx >> 5, d2 = idx & 31;
        ushort2 u = q2[(size_t)qr * 256 + d2];
        Qs[d2 * 2][qr]     = bf2f(u.x);
        Qs[d2 * 2 + 1][qr] = bf2f(u.y);
    }

    float m[4], l[4], o[4][4];
    #pragma unroll
    for (int j = 0; j < 4; ++j) {
        m[j] = -1e30f; l[j] = 0.f;
        #pragma unroll
        for (int i = 0; i < 4; ++i) o[j][i] = 0.f;
    }
    __syncthreads();

    for (int kt = 0; kt < 16; ++kt) {
        const ushort2* kv2 = reinterpret_cast<const ushort2*>(
            kvb + (size_t)(b * KVLEN + kt * 64) * 1024 + h * 64);
        #pragma unroll
        for (int r = 0; r < 8; ++r) {
            int idx = r * 256 + t;
            int kr = idx >> 5, d2 = idx & 31;
            ushort2 uk = kv2[(size_t)kr * 512 + d2];
            ushort2 uv = kv2[(size_t)kr * 512 + 256 + d2];
            Ks[d2 * 2][kr]     = bf2f(uk.x);
            Ks[d2 * 2 + 1][kr] = bf2f(uk.y);
            Vs[kr][d2 * 2]     = bf2f(uv.x);
            Vs[kr][d2 * 2 + 1] = bf2f(uv.y);
        }
        __syncthreads();

        float s[4][4];
        #pragma unroll
        for (int j = 0; j < 4; ++j)
            #pragma unroll
            for (int i = 0; i < 4; ++i) s[j][i] = 0.f;
        #pragma unroll 8
        for (int d = 0; d < 64; ++d) {
            float4 q4 = *reinterpret_cast<const float4*>(&Qs[d][ty * 4]);
            float4 k4 = *reinterpret_cast<const float4*>(&Ks[d][tx * 4]);
            float qv[4] = {q4.x, q4.y, q4.z, q4.w};
            float kv[4] = {k4.x, k4.y, k4.z, k4.w};
            #pragma unroll
            for (int j = 0; j < 4; ++j)
                #pragma unroll
                for (int i = 0; i < 4; ++i)
                    s[j][i] = fmaf(qv[j], kv[i], s[j][i]);
        }
        #pragma unroll
        for (int j = 0; j < 4; ++j)
            #pragma unroll
            for (int i = 0; i < 4; ++i) s[j][i] *= 0.125f;

        float p[4][4];
        #pragma unroll
        for (int j = 0; j < 4; ++j) {
            float mx = fmaxf(fmaxf(s[j][0], s[j][1]), fmaxf(s[j][2], s[j][3]));
            mx = fmaxf(mx, __shfl_xor(mx, 1));
            mx = fmaxf(mx, __shfl_xor(mx, 2));
            mx = fmaxf(mx, __shfl_xor(mx, 4));
            mx = fmaxf(mx, __shfl_xor(mx, 8));
            float mn = fmaxf(m[j], mx);
            float al = __expf(m[j] - mn);
            float rs = 0.f;
            #pragma unroll
            for (int i = 0; i < 4; ++i) {
                p[j][i] = __expf(s[j][i] - mn);
                rs += p[j][i];
            }
            rs += __shfl_xor(rs, 1);
            rs += __shfl_xor(rs, 2);
            rs += __shfl_xor(rs, 4);
            rs += __shfl_xor(rs, 8);
            l[j] = l[j] * al + rs;
            m[j] = mn;
            #pragma unroll
            for (int i = 0; i < 4; ++i) o[j][i] *= al;
        }
        __syncthreads();
        #pragma unroll
        for (int j = 0; j < 4; ++j)
            #pragma unroll
            for (int i = 0; i < 4; ++i)
                Ks[ty * 4 + j][tx * 4 + i] = p[j][i];
        __syncthreads();

        #pragma unroll 4
        for (int kr = 0; kr < 64; ++kr) {
            float4 v4 = *reinterpret_cast<const float4*>(&Vs[kr][tx * 4]);
            #pragma unroll
            for (int j = 0; j < 4; ++j) {
                float pj = Ks[ty * 4 + j][kr];
                o[j][0] = fmaf(pj, v4.x, o[j][0]);
                o[j][1] = fmaf(pj, v4.y, o[j][1]);
                o[j][2] = fmaf(pj, v4.z, o[j][2]);
                o[j][3] = fmaf(pj, v4.w, o[j][3]);
            }
        }
        __syncthreads();
    }

    #pragma unroll
    for (int j = 0; j < 4; ++j) {
        int gr = q_row0 + ty * 4 + j;
        float inv = 1.f / l[j];
        const float* fr = fq + (size_t)gr * DH;
        int d0 = tx * 4;
        float f0 = fr[d0], f1 = fr[d0 + 2];
        float s0, c0, s1, c1;
        sincosf(f0, &s0, &c0);
        sincosf(f1, &s1, &c1);
        float x0 = o[j][0] * inv, y0 = o[j][1] * inv;
        float x1 = o[j][2] * inv, y1 = o[j][3] * inv;
        float rr[4];
        rr[0] = x0 * c0 + y0 * s0;
        rr[1] = y0 * c0 - x0 * s0;
        rr[2] = x1 * c1 + y1 * s1;
        rr[3] = y1 * c1 - x1 * s1;
        ushort4 hh, ll;
        hh.x = f2bf(rr[0]); ll.x = f2bf(rr[0] - bf2f(hh.x));
        hh.y = f2bf(rr[1]); ll.y = f2bf(rr[1] - bf2f(hh.y));
        hh.z = f2bf(rr[2]); ll.z = f2bf(rr[2] - bf2f(hh.z));
        hh.w = f2bf(rr[3]); ll.w = f2bf(rr[3] - bf2f(hh.w));
        *reinterpret_cast<ushort4*>(aobH + (size_t)gr * 512 + h * 64 + d0) = hh;
        *reinterpret_cast<ushort4*>(aobL + (size_t)gr * 512 + h * 64 + d0) = ll;
    }
}

// ---------------------------------------------------------------------------
extern "C" void kernel_launch(void* const* d_in, const int* in_sizes, int n_in,
                              void* d_out, int out_size, void* d_ws, size_t ws_size,
                              hipStream_t stream) {
    const float* x_query   = (const float*)d_in[0];
    const float* x_context = (const float*)d_in[1];
    const float* fq        = (const float*)d_in[2];
    const float* fkv       = (const float*)d_in[3];
    const float* ln_q_g    = (const float*)d_in[4];
    const float* ln_q_b    = (const float*)d_in[5];
    const float* ln_c_g    = (const float*)d_in[6];
    const float* ln_c_b    = (const float*)d_in[7];
    const float* Wq        = (const float*)d_in[8];
    const float* Wkv       = (const float*)d_in[9];
    const float* Wout      = (const float*)d_in[10];
    const float* bout      = (const float*)d_in[11];
    float* out = (float*)d_out;

    unsigned short* xq     = (unsigned short*)d_ws;             // 8192*512
    unsigned short* xc     = xq + (size_t)NQ * 512;             // 16384*512
    unsigned short* WqT    = xc + (size_t)NKV * 512;            // 512*512
    unsigned short* WkvT   = WqT + 512 * 512;                   // 1024*512
    unsigned short* WoutTh = WkvT + 1024 * 512;                 // 512*512
    unsigned short* WoutTl = WoutTh + 512 * 512;                // 512*512
    unsigned short* qb     = WoutTl + 512 * 512;                // 8192*512
    unsigned short* kvb    = qb + (size_t)NQ * 512;             // 16384*1024
    unsigned short* aobH   = kvb + (size_t)NKV * 1024;          // 8192*512
    unsigned short* aobL   = aobH + (size_t)NQ * 512;           // 8192*512

    ln_cast_kernel<<<NQ / 4, 256, 0, stream>>>(x_query, ln_q_g, ln_q_b, xq, NQ);
    ln_cast_kernel<<<NKV / 4, 256, 0, stream>>>(x_context, ln_c_g, ln_c_b, xc, NKV);
    wt_cast_kernel<<<512 * 512 / 256, 256, 0, stream>>>(Wq, WqT, nullptr, 512);
    wt_cast_kernel<<<1024 * 512 / 256, 256, 0, stream>>>(Wkv, WkvT, nullptr, 1024);
    wt_cast_kernel<<<512 * 512 / 256, 256, 0, stream>>>(Wout, WoutTh, WoutTl, 512);

    mm_kernel<0><<<dim3(4, 64), 256, 0, stream>>>(
        xq, nullptr, WqT, nullptr, (void*)qb, fq, nullptr, 512);
    mm_kernel<1><<<dim3(8, 128), 256, 0, stream>>>(
        xc, nullptr, WkvT, nullptr, (void*)kvb, fkv, nullptr, 1024);

    attn_kernel<<<dim3(8, NHEADS, NBATCH), 256, 0, stream>>>(qb, kvb, fq, aobH, aobL);

    mm_kernel<2><<<dim3(4, 64), 256, 0, stream>>>(
        aobH, aobL, WoutTh, WoutTl, (void*)out, nullptr, bout, 512);
}

// Round 3
// 594.669 us; speedup vs baseline: 1.1139x; 1.0067x over previous
//
#include <hip/hip_runtime.h>

#define DIMK 512
#define NHEADS 8
#define DH 64
#define NBATCH 16
#define QLEN 512
#define KVLEN 1024
#define NQ (NBATCH*QLEN)     /* 8192  */
#define NKV (NBATCH*KVLEN)   /* 16384 */

typedef __attribute__((ext_vector_type(8))) short bf16x8;
typedef __attribute__((ext_vector_type(4))) float f32x4;
typedef __attribute__((ext_vector_type(8))) unsigned short us8;

__device__ __forceinline__ float bf2f(unsigned short u) {
    return __uint_as_float(((unsigned)u) << 16);
}
__device__ __forceinline__ unsigned short f2bf(float f) {
    unsigned u = __float_as_uint(f);
    return (unsigned short)((u + 0x7fffu + ((u >> 16) & 1u)) >> 16);
}
__device__ __forceinline__ void gl2lds16(const void* g, const void* lds) {
    __builtin_amdgcn_global_load_lds(
        (const __attribute__((address_space(1))) unsigned int*)g,
        (__attribute__((address_space(3))) unsigned int*)lds, 16, 0, 0);
}

// ---------------------------------------------------------------------------
// LN + bf16 cast, one wave per row of 512.
// ---------------------------------------------------------------------------
__global__ __launch_bounds__(256) void ln_cast_kernel(
    const float* __restrict__ x, const float* __restrict__ g,
    const float* __restrict__ bta, unsigned short* __restrict__ out, int nrows)
{
    int row  = blockIdx.x * 4 + (threadIdx.x >> 6);
    int lane = threadIdx.x & 63;
    if (row >= nrows) return;
    const float4* xr = reinterpret_cast<const float4*>(x + (size_t)row * DIMK);
    float4 v0 = xr[lane * 2];
    float4 v1 = xr[lane * 2 + 1];
    float s  = v0.x + v0.y + v0.z + v0.w + v1.x + v1.y + v1.z + v1.w;
    float sq = v0.x*v0.x + v0.y*v0.y + v0.z*v0.z + v0.w*v0.w
             + v1.x*v1.x + v1.y*v1.y + v1.z*v1.z + v1.w*v1.w;
    #pragma unroll
    for (int off = 32; off; off >>= 1) {
        s  += __shfl_xor(s, off);
        sq += __shfl_xor(sq, off);
    }
    float mu   = s * (1.0f / DIMK);
    float rstd = rsqrtf(sq * (1.0f / DIMK) - mu * mu + 1e-5f);
    const float4* g4 = reinterpret_cast<const float4*>(g + lane * 8);
    const float4* b4 = reinterpret_cast<const float4*>(bta + lane * 8);
    float4 g0 = g4[0], g1 = g4[1], b0 = b4[0], b1 = b4[1];
    us8 o;
    o[0] = f2bf((v0.x - mu) * rstd * g0.x + b0.x);
    o[1] = f2bf((v0.y - mu) * rstd * g0.y + b0.y);
    o[2] = f2bf((v0.z - mu) * rstd * g0.z + b0.z);
    o[3] = f2bf((v0.w - mu) * rstd * g0.w + b0.w);
    o[4] = f2bf((v1.x - mu) * rstd * g1.x + b1.x);
    o[5] = f2bf((v1.y - mu) * rstd * g1.y + b1.y);
    o[6] = f2bf((v1.z - mu) * rstd * g1.z + b1.z);
    o[7] = f2bf((v1.w - mu) * rstd * g1.w + b1.w);
    *reinterpret_cast<us8*>(out + (size_t)row * DIMK + lane * 8) = o;
}

// ---------------------------------------------------------------------------
// Weight transpose + bf16 cast (optional lo part). W is [512][N] -> T [N][512].
// ---------------------------------------------------------------------------
__global__ __launch_bounds__(256) void wt_cast_kernel(
    const float* __restrict__ W, unsigned short* __restrict__ Th,
    unsigned short* __restrict__ Tl, int N)
{
    int idx = blockIdx.x * 256 + threadIdx.x;   // n*512 + k
    int n = idx >> 9, k = idx & 511;
    float v = W[(size_t)k * N + n];
    unsigned short h = f2bf(v);
    Th[idx] = h;
    if (Tl) Tl[idx] = f2bf(v - bf2f(h));
}

// ---------------------------------------------------------------------------
// MFMA GEMM: 128x128 tile, BK=32, 4 waves, 2-phase double-buffered pipeline,
// XCD-swizzled 1D grid. A [M][512] bf16, B = W^T [N][512] bf16.
// MODE 0: C = rope(A@W) -> bf16      MODE 1: same, N=1024 (k and v roped)
// MODE 2: C = (Ah+Al)@(Wh+Wl) + bias -> f32 (split bf16, 3 MFMA)
// ---------------------------------------------------------------------------
template<int MODE>
__global__ __launch_bounds__(256) void mm_kernel(
    const unsigned short* __restrict__ Ah, const unsigned short* __restrict__ Al,
    const unsigned short* __restrict__ Bh, const unsigned short* __restrict__ Bl,
    void* __restrict__ Cout, const float* __restrict__ freqs,
    const float* __restrict__ bias)
{
    constexpr bool SPLIT = (MODE == 2);
    constexpr int NN  = (MODE == 1) ? 1024 : 512;
    constexpr int NCT = NN / 128;
    __shared__ __align__(16) unsigned short AsH[2][128 * 32];
    __shared__ __align__(16) unsigned short BsH[2][128 * 32];
    __shared__ __align__(16) unsigned short AsL[SPLIT ? 2 : 1][SPLIT ? 128 * 32 : 8];
    __shared__ __align__(16) unsigned short BsL[SPLIT ? 2 : 1][SPLIT ? 128 * 32 : 8];

    const int t = threadIdx.x;
    const int lane = t & 63, w = t >> 6;
    const int l15 = lane & 15, l4 = lane >> 4;
    const int wr = w >> 1, wc = w & 1;

    // bijective XCD swizzle: each XCD owns a contiguous chunk of tile space,
    // col-tile fastest inside the chunk -> A-panel L2 reuse within one XCD.
    const int nwg  = gridDim.x;
    const int tile = (blockIdx.x & 7) * (nwg >> 3) + (blockIdx.x >> 3);
    const int row0 = (tile / NCT) * 128;
    const int col0 = (tile % NCT) * 128;

    const int stRow = lane >> 2;          // row within 16-row sub-block
    const int stK   = (lane & 3) * 8;     // element offset within 32-elem row

    auto stage = [&](int buf, int k0) {
        constexpr int NI = SPLIT ? 8 : 4;
        #pragma unroll
        for (int j = 0; j < NI; ++j) {
            int id  = w * NI + j;
            int mat = id >> 3;            // 0:AH 1:BH 2:AL 3:BL
            int sub = id & 7;
            int row = sub * 16 + stRow;
            const unsigned short* gsrc =
                (mat == 0) ? Ah + (size_t)(row0 + row) * 512 :
                (mat == 1) ? Bh + (size_t)(col0 + row) * 512 :
                (mat == 2) ? Al + (size_t)(row0 + row) * 512 :
                             Bl + (size_t)(col0 + row) * 512;
            unsigned short* ldst =
                (mat == 0) ? &AsH[buf][0] :
                (mat == 1) ? &BsH[buf][0] :
                (mat == 2) ? &AsL[SPLIT ? buf : 0][0] :
                             &BsL[SPLIT ? buf : 0][0];
            gl2lds16(gsrc + k0 + stK, ldst + sub * 512);
        }
    };

    f32x4 acc[4][4];
    #pragma unroll
    for (int m = 0; m < 4; ++m)
        #pragma unroll
        for (int n = 0; n < 4; ++n)
            acc[m][n] = (f32x4){0.f, 0.f, 0.f, 0.f};

    stage(0, 0);
    __syncthreads();

    for (int ks = 0; ks < 16; ++ks) {
        const int cur = ks & 1;
        if (ks < 15) stage(cur ^ 1, (ks + 1) * 32);   // prefetch next tile

        bf16x8 fah[4], fbh[4];
        #pragma unroll
        for (int m = 0; m < 4; ++m)
            fah[m] = *reinterpret_cast<const bf16x8*>(&AsH[cur][(wr*64 + m*16 + l15) * 32 + l4*8]);
        #pragma unroll
        for (int n = 0; n < 4; ++n)
            fbh[n] = *reinterpret_cast<const bf16x8*>(&BsH[cur][(wc*64 + n*16 + l15) * 32 + l4*8]);
        if constexpr (SPLIT) {
            bf16x8 fal[4], fbl[4];
            #pragma unroll
            for (int m = 0; m < 4; ++m)
                fal[m] = *reinterpret_cast<const bf16x8*>(&AsL[cur][(wr*64 + m*16 + l15) * 32 + l4*8]);
            #pragma unroll
            for (int n = 0; n < 4; ++n)
                fbl[n] = *reinterpret_cast<const bf16x8*>(&BsL[cur][(wc*64 + n*16 + l15) * 32 + l4*8]);
            #pragma unroll
            for (int m = 0; m < 4; ++m)
                #pragma unroll
                for (int n = 0; n < 4; ++n) {
                    acc[m][n] = __builtin_amdgcn_mfma_f32_16x16x32_bf16(fah[m], fbh[n], acc[m][n], 0, 0, 0);
                    acc[m][n] = __builtin_amdgcn_mfma_f32_16x16x32_bf16(fah[m], fbl[n], acc[m][n], 0, 0, 0);
                    acc[m][n] = __builtin_amdgcn_mfma_f32_16x16x32_bf16(fal[m], fbh[n], acc[m][n], 0, 0, 0);
                }
        } else {
            #pragma unroll
            for (int m = 0; m < 4; ++m)
                #pragma unroll
                for (int n = 0; n < 4; ++n)
                    acc[m][n] = __builtin_amdgcn_mfma_f32_16x16x32_bf16(fah[m], fbh[n], acc[m][n], 0, 0, 0);
        }
        __syncthreads();   // drains prefetch (vmcnt 0) + readers done with cur
    }

    // epilogue: C/D layout col=lane&15, row=(lane>>4)*4+j
    #pragma unroll
    for (int m = 0; m < 4; ++m) {
        #pragma unroll
        for (int n = 0; n < 4; ++n) {
            #pragma unroll
            for (int j = 0; j < 4; ++j) {
                float v = acc[m][n][j];
                int gr = row0 + wr*64 + m*16 + l4*4 + j;
                int gc = col0 + wc*64 + n*16 + l15;
                if constexpr (MODE == 2) {
                    ((float*)Cout)[(size_t)gr * NN + gc] = v + bias[gc];
                } else {
                    float pv = __shfl_xor(v, 1);         // partner column of rope pair
                    float f = freqs[(size_t)gr * DH + (gc & 63)];
                    float sn, cs;
                    sincosf(f, &sn, &cs);
                    float nv = (lane & 1) ? fmaf(pv, sn, v * cs)    // odd:  y c + x s
                                          : fmaf(-pv, sn, v * cs);  // even: x c - y s
                    ((unsigned short*)Cout)[(size_t)gr * NN + gc] = f2bf(nv);
                }
            }
        }
    }
}

// ---------------------------------------------------------------------------
// Flash attention (f32 compute, bf16 in, split-bf16 out). Unchanged math.
// ---------------------------------------------------------------------------
__global__ __launch_bounds__(256) void attn_kernel(
    const unsigned short* __restrict__ qb, const unsigned short* __restrict__ kvb,
    const float* __restrict__ fq, unsigned short* __restrict__ aobH,
    unsigned short* __restrict__ aobL)
{
    const int qt = blockIdx.x;   // 0..7
    const int h  = blockIdx.y;   // 0..7
    const int b  = blockIdx.z;   // 0..15
    const int t  = threadIdx.x;
    const int tx = t & 15;
    const int ty = t >> 4;

    __shared__ float Qs[64][68];
    __shared__ float Ks[64][68];
    __shared__ float Vs[64][68];

    const int q_row0 = b * QLEN + qt * 64;

    const ushort2* q2 = reinterpret_cast<const ushort2*>(qb + (size_t)q_row0 * 512 + h * 64);
    #pragma unroll
    for (int r = 0; r < 8; ++r) {
        int idx = r * 256 + t;
        int qr = idx >> 5, d2 = idx & 31;
        ushort2 u = q2[(size_t)qr * 256 + d2];
        Qs[d2 * 2][qr]     = bf2f(u.x);
        Qs[d2 * 2 + 1][qr] = bf2f(u.y);
    }

    float m[4], l[4], o[4][4];
    #pragma unroll
    for (int j = 0; j < 4; ++j) {
        m[j] = -1e30f; l[j] = 0.f;
        #pragma unroll
        for (int i = 0; i < 4; ++i) o[j][i] = 0.f;
    }
    __syncthreads();

    for (int kt = 0; kt < 16; ++kt) {
        const ushort2* kv2 = reinterpret_cast<const ushort2*>(
            kvb + (size_t)(b * KVLEN + kt * 64) * 1024 + h * 64);
        #pragma unroll
        for (int r = 0; r < 8; ++r) {
            int idx = r * 256 + t;
            int kr = idx >> 5, d2 = idx & 31;
            ushort2 uk = kv2[(size_t)kr * 512 + d2];
            ushort2 uv = kv2[(size_t)kr * 512 + 256 + d2];
            Ks[d2 * 2][kr]     = bf2f(uk.x);
            Ks[d2 * 2 + 1][kr] = bf2f(uk.y);
            Vs[kr][d2 * 2]     = bf2f(uv.x);
            Vs[kr][d2 * 2 + 1] = bf2f(uv.y);
        }
        __syncthreads();

        float s[4][4];
        #pragma unroll
        for (int j = 0; j < 4; ++j)
            #pragma unroll
            for (int i = 0; i < 4; ++i) s[j][i] = 0.f;
        #pragma unroll 8
        for (int d = 0; d < 64; ++d) {
            float4 q4 = *reinterpret_cast<const float4*>(&Qs[d][ty * 4]);
            float4 k4 = *reinterpret_cast<const float4*>(&Ks[d][tx * 4]);
            float qv[4] = {q4.x, q4.y, q4.z, q4.w};
            float kv[4] = {k4.x, k4.y, k4.z, k4.w};
            #pragma unroll
            for (int j = 0; j < 4; ++j)
                #pragma unroll
                for (int i = 0; i < 4; ++i)
                    s[j][i] = fmaf(qv[j], kv[i], s[j][i]);
        }
        #pragma unroll
        for (int j = 0; j < 4; ++j)
            #pragma unroll
            for (int i = 0; i < 4; ++i) s[j][i] *= 0.125f;

        float p[4][4];
        #pragma unroll
        for (int j = 0; j < 4; ++j) {
            float mx = fmaxf(fmaxf(s[j][0], s[j][1]), fmaxf(s[j][2], s[j][3]));
            mx = fmaxf(mx, __shfl_xor(mx, 1));
            mx = fmaxf(mx, __shfl_xor(mx, 2));
            mx = fmaxf(mx, __shfl_xor(mx, 4));
            mx = fmaxf(mx, __shfl_xor(mx, 8));
            float mn = fmaxf(m[j], mx);
            float al = __expf(m[j] - mn);
            float rs = 0.f;
            #pragma unroll
            for (int i = 0; i < 4; ++i) {
                p[j][i] = __expf(s[j][i] - mn);
                rs += p[j][i];
            }
            rs += __shfl_xor(rs, 1);
            rs += __shfl_xor(rs, 2);
            rs += __shfl_xor(rs, 4);
            rs += __shfl_xor(rs, 8);
            l[j] = l[j] * al + rs;
            m[j] = mn;
            #pragma unroll
            for (int i = 0; i < 4; ++i) o[j][i] *= al;
        }
        __syncthreads();
        #pragma unroll
        for (int j = 0; j < 4; ++j)
            #pragma unroll
            for (int i = 0; i < 4; ++i)
                Ks[ty * 4 + j][tx * 4 + i] = p[j][i];
        __syncthreads();

        #pragma unroll 4
        for (int kr = 0; kr < 64; ++kr) {
            float4 v4 = *reinterpret_cast<const float4*>(&Vs[kr][tx * 4]);
            #pragma unroll
            for (int j = 0; j < 4; ++j) {
                float pj = Ks[ty * 4 + j][kr];
                o[j][0] = fmaf(pj, v4.x, o[j][0]);
                o[j][1] = fmaf(pj, v4.y, o[j][1]);
                o[j][2] = fmaf(pj, v4.z, o[j][2]);
                o[j][3] = fmaf(pj, v4.w, o[j][3]);
            }
        }
        __syncthreads();
    }

    #pragma unroll
    for (int j = 0; j < 4; ++j) {
        int gr = q_row0 + ty * 4 + j;
        float inv = 1.f / l[j];
        const float* fr = fq + (size_t)gr * DH;
        int d0 = tx * 4;
        float f0 = fr[d0], f1 = fr[d0 + 2];
        float s0, c0, s1, c1;
        sincosf(f0, &s0, &c0);
        sincosf(f1, &s1, &c1);
        float x0 = o[j][0] * inv, y0 = o[j][1] * inv;
        float x1 = o[j][2] * inv, y1 = o[j][3] * inv;
        float rr[4];
        rr[0] = x0 * c0 + y0 * s0;
        rr[1] = y0 * c0 - x0 * s0;
        rr[2] = x1 * c1 + y1 * s1;
        rr[3] = y1 * c1 - x1 * s1;
        ushort4 hh, ll;
        hh.x = f2bf(rr[0]); ll.x = f2bf(rr[0] - bf2f(hh.x));
        hh.y = f2bf(rr[1]); ll.y = f2bf(rr[1] - bf2f(hh.y));
        hh.z = f2bf(rr[2]); ll.z = f2bf(rr[2] - bf2f(hh.z));
        hh.w = f2bf(rr[3]); ll.w = f2bf(rr[3] - bf2f(hh.w));
        *reinterpret_cast<ushort4*>(aobH + (size_t)gr * 512 + h * 64 + d0) = hh;
        *reinterpret_cast<ushort4*>(aobL + (size_t)gr * 512 + h * 64 + d0) = ll;
    }
}

// ---------------------------------------------------------------------------
extern "C" void kernel_launch(void* const* d_in, const int* in_sizes, int n_in,
                              void* d_out, int out_size, void* d_ws, size_t ws_size,
                              hipStream_t stream) {
    const float* x_query   = (const float*)d_in[0];
    const float* x_context = (const float*)d_in[1];
    const float* fq        = (const float*)d_in[2];
    const float* fkv       = (const float*)d_in[3];
    const float* ln_q_g    = (const float*)d_in[4];
    const float* ln_q_b    = (const float*)d_in[5];
    const float* ln_c_g    = (const float*)d_in[6];
    const float* ln_c_b    = (const float*)d_in[7];
    const float* Wq        = (const float*)d_in[8];
    const float* Wkv       = (const float*)d_in[9];
    const float* Wout      = (const float*)d_in[10];
    const float* bout      = (const float*)d_in[11];
    float* out = (float*)d_out;

    unsigned short* xq     = (unsigned short*)d_ws;             // 8192*512
    unsigned short* xc     = xq + (size_t)NQ * 512;             // 16384*512
    unsigned short* WqT    = xc + (size_t)NKV * 512;            // 512*512
    unsigned short* WkvT   = WqT + 512 * 512;                   // 1024*512
    unsigned short* WoutTh = WkvT + 1024 * 512;                 // 512*512
    unsigned short* WoutTl = WoutTh + 512 * 512;                // 512*512
    unsigned short* qb     = WoutTl + 512 * 512;                // 8192*512
    unsigned short* kvb    = qb + (size_t)NQ * 512;             // 16384*1024
    unsigned short* aobH   = kvb + (size_t)NKV * 1024;          // 8192*512
    unsigned short* aobL   = aobH + (size_t)NQ * 512;           // 8192*512

    ln_cast_kernel<<<NQ / 4, 256, 0, stream>>>(x_query, ln_q_g, ln_q_b, xq, NQ);
    ln_cast_kernel<<<NKV / 4, 256, 0, stream>>>(x_context, ln_c_g, ln_c_b, xc, NKV);
    wt_cast_kernel<<<512 * 512 / 256, 256, 0, stream>>>(Wq, WqT, nullptr, 512);
    wt_cast_kernel<<<1024 * 512 / 256, 256, 0, stream>>>(Wkv, WkvT, nullptr, 1024);
    wt_cast_kernel<<<512 * 512 / 256, 256, 0, stream>>>(Wout, WoutTh, WoutTl, 512);

    mm_kernel<0><<<256, 256, 0, stream>>>(
        xq, nullptr, WqT, nullptr, (void*)qb, fq, nullptr);
    mm_kernel<1><<<1024, 256, 0, stream>>>(
        xc, nullptr, WkvT, nullptr, (void*)kvb, fkv, nullptr);

    attn_kernel<<<dim3(8, NHEADS, NBATCH), 256, 0, stream>>>(qb, kvb, fq, aobH, aobL);

    mm_kernel<2><<<256, 256, 0, stream>>>(
        aobH, aobL, WoutTh, WoutTl, (void*)out, nullptr, bout);
}

// Round 5
// 420.195 us; speedup vs baseline: 1.5764x; 1.4152x over previous
//
#include <hip/hip_runtime.h>

#define DIMK 512
#define NHEADS 8
#define DH 64
#define NBATCH 16
#define QLEN 512
#define KVLEN 1024
#define NQ (NBATCH*QLEN)     /* 8192  */
#define NKV (NBATCH*KVLEN)   /* 16384 */

typedef __attribute__((ext_vector_type(8))) short bf16x8;
typedef __attribute__((ext_vector_type(4))) float f32x4;
typedef __attribute__((ext_vector_type(8))) unsigned short us8;

__device__ __forceinline__ float bf2f(unsigned short u) {
    return __uint_as_float(((unsigned)u) << 16);
}
__device__ __forceinline__ unsigned short f2bf(float f) {
    unsigned u = __float_as_uint(f);
    return (unsigned short)((u + 0x7fffu + ((u >> 16) & 1u)) >> 16);
}
__device__ __forceinline__ void gl2lds16(const void* g, const void* lds) {
    __builtin_amdgcn_global_load_lds(
        (const __attribute__((address_space(1))) unsigned int*)g,
        (__attribute__((address_space(3))) unsigned int*)lds, 16, 0, 0);
}

// ---------------------------------------------------------------------------
// LN + bf16 cast, one wave per row of 512.
// ---------------------------------------------------------------------------
__global__ __launch_bounds__(256) void ln_cast_kernel(
    const float* __restrict__ x, const float* __restrict__ g,
    const float* __restrict__ bta, unsigned short* __restrict__ out, int nrows)
{
    int row  = blockIdx.x * 4 + (threadIdx.x >> 6);
    int lane = threadIdx.x & 63;
    if (row >= nrows) return;
    const float4* xr = reinterpret_cast<const float4*>(x + (size_t)row * DIMK);
    float4 v0 = xr[lane * 2];
    float4 v1 = xr[lane * 2 + 1];
    float s  = v0.x + v0.y + v0.z + v0.w + v1.x + v1.y + v1.z + v1.w;
    float sq = v0.x*v0.x + v0.y*v0.y + v0.z*v0.z + v0.w*v0.w
             + v1.x*v1.x + v1.y*v1.y + v1.z*v1.z + v1.w*v1.w;
    #pragma unroll
    for (int off = 32; off; off >>= 1) {
        s  += __shfl_xor(s, off);
        sq += __shfl_xor(sq, off);
    }
    float mu   = s * (1.0f / DIMK);
    float rstd = rsqrtf(sq * (1.0f / DIMK) - mu * mu + 1e-5f);
    const float4* g4 = reinterpret_cast<const float4*>(g + lane * 8);
    const float4* b4 = reinterpret_cast<const float4*>(bta + lane * 8);
    float4 g0 = g4[0], g1 = g4[1], b0 = b4[0], b1 = b4[1];
    us8 o;
    o[0] = f2bf((v0.x - mu) * rstd * g0.x + b0.x);
    o[1] = f2bf((v0.y - mu) * rstd * g0.y + b0.y);
    o[2] = f2bf((v0.z - mu) * rstd * g0.z + b0.z);
    o[3] = f2bf((v0.w - mu) * rstd * g0.w + b0.w);
    o[4] = f2bf((v1.x - mu) * rstd * g1.x + b1.x);
    o[5] = f2bf((v1.y - mu) * rstd * g1.y + b1.y);
    o[6] = f2bf((v1.z - mu) * rstd * g1.z + b1.z);
    o[7] = f2bf((v1.w - mu) * rstd * g1.w + b1.w);
    *reinterpret_cast<us8*>(out + (size_t)row * DIMK + lane * 8) = o;
}

// ---------------------------------------------------------------------------
// Weight transpose + bf16 cast (optional lo part). W is [512][N] -> T [N][512].
// ---------------------------------------------------------------------------
__global__ __launch_bounds__(256) void wt_cast_kernel(
    const float* __restrict__ W, unsigned short* __restrict__ Th,
    unsigned short* __restrict__ Tl, int N)
{
    int idx = blockIdx.x * 256 + threadIdx.x;   // n*512 + k
    int n = idx >> 9, k = idx & 511;
    float v = W[(size_t)k * N + n];
    unsigned short h = f2bf(v);
    Th[idx] = h;
    if (Tl) Tl[idx] = f2bf(v - bf2f(h));
}

// ---------------------------------------------------------------------------
// V transpose: kvb v-part [b*1024+k][512 + h*64 + d] -> vT[(b*8+h)*64 + d][k].
// One block per (b, h, 64-k tile).
// ---------------------------------------------------------------------------
__global__ __launch_bounds__(256) void vtrans_kernel(
    const unsigned short* __restrict__ kv, unsigned short* __restrict__ vT)
{
    __shared__ unsigned short tile[64][80];   // 160B rows: 16B-aligned
    const int bid = blockIdx.x;               // b*128 + h*16 + kt
    const int kt = bid & 15, h = (bid >> 4) & 7, b = bid >> 7;
    const int t = threadIdx.x;
    const int r = t >> 3, c8 = (t & 7) * 8;
    #pragma unroll
    for (int p = 0; p < 2; ++p) {
        int k = p * 32 + r;
        us8 v = *reinterpret_cast<const us8*>(
            &kv[(size_t)(b * 1024 + kt * 64 + k) * 1024 + 512 + h * 64 + c8]);
        *reinterpret_cast<us8*>(&tile[k][c8]) = v;
    }
    __syncthreads();
    #pragma unroll
    for (int p = 0; p < 2; ++p) {
        int u = p * 256 + t;
        int d = u >> 3, k8 = (u & 7) * 8;
        us8 o;
        #pragma unroll
        for (int i = 0; i < 8; ++i) o[i] = tile[k8 + i][d];
        *reinterpret_cast<us8*>(
            &vT[(size_t)((b * 8 + h) * 64 + d) * 1024 + kt * 64 + k8]) = o;
    }
}

// ---------------------------------------------------------------------------
// MFMA GEMM: 128x128 tile, BK=32, 4 waves, 2-phase double-buffered pipeline,
// XCD-swizzled 1D grid. A [M][512] bf16, B = W^T [N][512] bf16.
// MODE 0: C = rope(A@W) -> bf16      MODE 1: same, N=1024 (k and v roped)
// MODE 2: C = (Ah+Al)@(Wh+Wl) + bias -> f32 (split bf16, 3 MFMA)
// ---------------------------------------------------------------------------
template<int MODE>
__global__ __launch_bounds__(256) void mm_kernel(
    const unsigned short* __restrict__ Ah, const unsigned short* __restrict__ Al,
    const unsigned short* __restrict__ Bh, const unsigned short* __restrict__ Bl,
    void* __restrict__ Cout, const float* __restrict__ freqs,
    const float* __restrict__ bias)
{
    constexpr bool SPLIT = (MODE == 2);
    constexpr int NN  = (MODE == 1) ? 1024 : 512;
    constexpr int NCT = NN / 128;
    __shared__ __align__(16) unsigned short AsH[2][128 * 32];
    __shared__ __align__(16) unsigned short BsH[2][128 * 32];
    __shared__ __align__(16) unsigned short AsL[SPLIT ? 2 : 1][SPLIT ? 128 * 32 : 8];
    __shared__ __align__(16) unsigned short BsL[SPLIT ? 2 : 1][SPLIT ? 128 * 32 : 8];

    const int t = threadIdx.x;
    const int lane = t & 63, w = t >> 6;
    const int l15 = lane & 15, l4 = lane >> 4;
    const int wr = w >> 1, wc = w & 1;

    const int nwg  = gridDim.x;
    const int tile = (blockIdx.x & 7) * (nwg >> 3) + (blockIdx.x >> 3);
    const int row0 = (tile / NCT) * 128;
    const int col0 = (tile % NCT) * 128;

    const int stRow = lane >> 2;
    const int stK   = (lane & 3) * 8;

    auto stage = [&](int buf, int k0) {
        constexpr int NI = SPLIT ? 8 : 4;
        #pragma unroll
        for (int j = 0; j < NI; ++j) {
            int id  = w * NI + j;
            int mat = id >> 3;
            int sub = id & 7;
            int row = sub * 16 + stRow;
            const unsigned short* gsrc =
                (mat == 0) ? Ah + (size_t)(row0 + row) * 512 :
                (mat == 1) ? Bh + (size_t)(col0 + row) * 512 :
                (mat == 2) ? Al + (size_t)(row0 + row) * 512 :
                             Bl + (size_t)(col0 + row) * 512;
            unsigned short* ldst =
                (mat == 0) ? &AsH[buf][0] :
                (mat == 1) ? &BsH[buf][0] :
                (mat == 2) ? &AsL[SPLIT ? buf : 0][0] :
                             &BsL[SPLIT ? buf : 0][0];
            gl2lds16(gsrc + k0 + stK, ldst + sub * 512);
        }
    };

    f32x4 acc[4][4];
    #pragma unroll
    for (int m = 0; m < 4; ++m)
        #pragma unroll
        for (int n = 0; n < 4; ++n)
            acc[m][n] = (f32x4){0.f, 0.f, 0.f, 0.f};

    stage(0, 0);
    __syncthreads();

    for (int ks = 0; ks < 16; ++ks) {
        const int cur = ks & 1;
        if (ks < 15) stage(cur ^ 1, (ks + 1) * 32);

        bf16x8 fah[4], fbh[4];
        #pragma unroll
        for (int m = 0; m < 4; ++m)
            fah[m] = *reinterpret_cast<const bf16x8*>(&AsH[cur][(wr*64 + m*16 + l15) * 32 + l4*8]);
        #pragma unroll
        for (int n = 0; n < 4; ++n)
            fbh[n] = *reinterpret_cast<const bf16x8*>(&BsH[cur][(wc*64 + n*16 + l15) * 32 + l4*8]);
        if constexpr (SPLIT) {
            bf16x8 fal[4], fbl[4];
            #pragma unroll
            for (int m = 0; m < 4; ++m)
                fal[m] = *reinterpret_cast<const bf16x8*>(&AsL[cur][(wr*64 + m*16 + l15) * 32 + l4*8]);
            #pragma unroll
            for (int n = 0; n < 4; ++n)
                fbl[n] = *reinterpret_cast<const bf16x8*>(&BsL[cur][(wc*64 + n*16 + l15) * 32 + l4*8]);
            #pragma unroll
            for (int m = 0; m < 4; ++m)
                #pragma unroll
                for (int n = 0; n < 4; ++n) {
                    acc[m][n] = __builtin_amdgcn_mfma_f32_16x16x32_bf16(fah[m], fbh[n], acc[m][n], 0, 0, 0);
                    acc[m][n] = __builtin_amdgcn_mfma_f32_16x16x32_bf16(fah[m], fbl[n], acc[m][n], 0, 0, 0);
                    acc[m][n] = __builtin_amdgcn_mfma_f32_16x16x32_bf16(fal[m], fbh[n], acc[m][n], 0, 0, 0);
                }
        } else {
            #pragma unroll
            for (int m = 0; m < 4; ++m)
                #pragma unroll
                for (int n = 0; n < 4; ++n)
                    acc[m][n] = __builtin_amdgcn_mfma_f32_16x16x32_bf16(fah[m], fbh[n], acc[m][n], 0, 0, 0);
        }
        __syncthreads();
    }

    #pragma unroll
    for (int m = 0; m < 4; ++m) {
        #pragma unroll
        for (int n = 0; n < 4; ++n) {
            #pragma unroll
            for (int j = 0; j < 4; ++j) {
                float v = acc[m][n][j];
                int gr = row0 + wr*64 + m*16 + l4*4 + j;
                int gc = col0 + wc*64 + n*16 + l15;
                if constexpr (MODE == 2) {
                    ((float*)Cout)[(size_t)gr * NN + gc] = v + bias[gc];
                } else {
                    float pv = __shfl_xor(v, 1);
                    float f = freqs[(size_t)gr * DH + (gc & 63)];
                    float sn, cs;
                    sincosf(f, &sn, &cs);
                    float nv = (lane & 1) ? fmaf(pv, sn, v * cs)
                                          : fmaf(-pv, sn, v * cs);
                    ((unsigned short*)Cout)[(size_t)gr * NN + gc] = f2bf(nv);
                }
            }
        }
    }
}

// ---------------------------------------------------------------------------
// MFMA flash attention v2. Block = (b, h, 64 q-rows); 4 waves x 16 q-rows.
// QK^T swapped (S^T = mfma(K, Q), both frags straight from global) -> in-lane
// online softmax (q = lane&15) -> split-bf16 P via wave-private swizzled LDS
// round-trip -> PV with the same verified 16x16x32 MFMA, V^T staged by linear
// global_load_lds from a pre-transposed vT with inverse-swizzled source.
// ---------------------------------------------------------------------------
__global__ __launch_bounds__(256) void attn_kernel(
    const unsigned short* __restrict__ qb, const unsigned short* __restrict__ kvb,
    const unsigned short* __restrict__ vT, const float* __restrict__ fq,
    unsigned short* __restrict__ aobH, unsigned short* __restrict__ aobL)
{
    // V^T tile, double buffered: [buf][d 64][k 64, col-swizzled ^((d&7)<<3)]
    __shared__ __align__(16) unsigned short Vs[2][4096];
    // P scratch, wave-private: [wave][hi/lo][q 16][k 64, col-swizzled ^((q&7)<<3)]
    __shared__ __align__(16) unsigned short Ps[4][2][1024];

    const int bid  = blockIdx.x;
    const int tile = (bid & 7) * 128 + (bid >> 3);   // XCD-chunked: qt fastest
    const int qt = tile & 7, h = (tile >> 3) & 7, b = tile >> 6;
    const int t = threadIdx.x, lane = t & 63, w = t >> 6;
    const int l15 = lane & 15, l4 = lane >> 4;
    const int bh = b * 8 + h;

    const int q_row0 = b * QLEN + qt * 64 + w * 16;   // wave's first q-row
    const size_t kvr0 = (size_t)b * KVLEN;

    // Q B-frags: lane holds Q[q=l15][d = half*32 + l4*8 + e]
    bf16x8 qf0 = *reinterpret_cast<const bf16x8*>(
        &qb[(size_t)(q_row0 + l15) * 512 + h * 64 + l4 * 8]);
    bf16x8 qf1 = *reinterpret_cast<const bf16x8*>(
        &qb[(size_t)(q_row0 + l15) * 512 + h * 64 + 32 + l4 * 8]);

    // stage V^T tile kt into Vs[buf]: linear LDS dest, source k-chunk
    // inverse-swizzled so reads at col ^((d&7)<<3) see element k.
    auto stageVT = [&](int buf, int kt) {
        #pragma unroll
        for (int i = 0; i < 2; ++i) {
            const int dbase = (w * 2 + i) * 8;
            const int dlo = lane >> 3;        // d - dbase (0..7)
            const int cb  = lane & 7;         // 16B chunk within row
            gl2lds16(&vT[(size_t)(bh * 64 + dbase + dlo) * 1024 + kt * 64
                         + ((cb ^ dlo) * 8)],
                     &Vs[buf][dbase * 64]);
        }
    };

    f32x4 o[4];
    #pragma unroll
    for (int dt = 0; dt < 4; ++dt) o[dt] = (f32x4){0.f, 0.f, 0.f, 0.f};
    float mrun = -1e30f, lrun = 0.f;

    unsigned short* pw = &Ps[w][0][0];

    stageVT(0, 0);

    for (int kt = 0; kt < 16; ++kt) {
        __syncthreads();   // stage(kt) complete; all reads of other buf done
        const int cur = kt & 1;

        // K A-frags straight from global: A[row = k-sub = l15][d = half*32+l4*8+e]
        bf16x8 kf[4][2];
        #pragma unroll
        for (int n = 0; n < 4; ++n) {
            const unsigned short* krow =
                &kvb[(kvr0 + kt * 64 + n * 16 + l15) * 1024 + h * 64];
            kf[n][0] = *reinterpret_cast<const bf16x8*>(&krow[l4 * 8]);
            kf[n][1] = *reinterpret_cast<const bf16x8*>(&krow[32 + l4 * 8]);
        }
        if (kt < 15) stageVT(cur ^ 1, kt + 1);

        // S^T = K Q^T: lane holds S[k = n*16 + l4*4 + j][q = l15]
        f32x4 s[4];
        #pragma unroll
        for (int n = 0; n < 4; ++n) {
            f32x4 a = (f32x4){0.f, 0.f, 0.f, 0.f};
            a = __builtin_amdgcn_mfma_f32_16x16x32_bf16(kf[n][0], qf0, a, 0, 0, 0);
            a = __builtin_amdgcn_mfma_f32_16x16x32_bf16(kf[n][1], qf1, a, 0, 0, 0);
            s[n] = a;
        }

        // online softmax for q = l15 (16 in-lane values + xor 16,32 over l4)
        float mx = -1e30f;
        #pragma unroll
        for (int n = 0; n < 4; ++n)
            #pragma unroll
            for (int j = 0; j < 4; ++j) {
                s[n][j] *= 0.125f;
                mx = fmaxf(mx, s[n][j]);
            }
        mx = fmaxf(mx, __shfl_xor(mx, 16));
        mx = fmaxf(mx, __shfl_xor(mx, 32));
        float mnew = fmaxf(mrun, mx);
        float al = __expf(mrun - mnew);
        float rs = 0.f;
        unsigned short ph[4][4], pl[4][4];
        #pragma unroll
        for (int n = 0; n < 4; ++n)
            #pragma unroll
            for (int j = 0; j < 4; ++j) {
                float p = __expf(s[n][j] - mnew);
                rs += p;
                unsigned u = __float_as_uint(p);
                ph[n][j] = (unsigned short)(u >> 16);             // trunc-hi
                float hi = __uint_as_float(u & 0xffff0000u);
                pl[n][j] = (unsigned short)(__float_as_uint(p - hi) >> 16);
            }
        rs += __shfl_xor(rs, 16);
        rs += __shfl_xor(rs, 32);
        lrun = lrun * al + rs;
        mrun = mnew;

        // write P (hi/lo) to wave-private swizzled LDS: element k at
        // short-col k ^ ((q&7)<<3) of row q
        #pragma unroll
        for (int n = 0; n < 4; ++n) {
            int idx = l15 * 64 + ((n * 16 + l4 * 4) ^ ((l15 & 7) << 3));
            *reinterpret_cast<ushort4*>(&pw[idx]) =
                make_ushort4(ph[n][0], ph[n][1], ph[n][2], ph[n][3]);
            *reinterpret_cast<ushort4*>(&pw[1024 + idx]) =
                make_ushort4(pl[n][0], pl[n][1], pl[n][2], pl[n][3]);
        }

        // rescale O (rows q = l4*4 + r; alpha lives at lane q)
        float a0 = __shfl(al, l4 * 4 + 0);
        float a1 = __shfl(al, l4 * 4 + 1);
        float a2 = __shfl(al, l4 * 4 + 2);
        float a3 = __shfl(al, l4 * 4 + 3);
        #pragma unroll
        for (int dt = 0; dt < 4; ++dt) {
            o[dt][0] *= a0; o[dt][1] *= a1; o[dt][2] *= a2; o[dt][3] *= a3;
        }

        // P A-frags: P[q = l15][k = c*32 + l4*8 + e]
        bf16x8 pfh[2], pfl[2];
        #pragma unroll
        for (int c = 0; c < 2; ++c) {
            int idx = l15 * 64 + ((c * 32 + l4 * 8) ^ ((l15 & 7) << 3));
            pfh[c] = *reinterpret_cast<const bf16x8*>(&pw[idx]);
            pfl[c] = *reinterpret_cast<const bf16x8*>(&pw[1024 + idx]);
        }
        // V B-frags: V[k = c*32 + l4*8 + e][d = dt*16 + l15]
        #pragma unroll
        for (int dt = 0; dt < 4; ++dt) {
            int d = dt * 16 + l15;
            #pragma unroll
            for (int c = 0; c < 2; ++c) {
                int vidx = d * 64 + ((c * 32 + l4 * 8) ^ ((d & 7) << 3));
                bf16x8 vf = *reinterpret_cast<const bf16x8*>(&Vs[cur][vidx]);
                o[dt] = __builtin_amdgcn_mfma_f32_16x16x32_bf16(pfh[c], vf, o[dt], 0, 0, 0);
                o[dt] = __builtin_amdgcn_mfma_f32_16x16x32_bf16(pfl[c], vf, o[dt], 0, 0, 0);
            }
        }
    }

    // epilogue: normalize + inverse rope + split-bf16 store
    // o[dt][r] = O[q = l4*4 + r][d = dt*16 + l15]
    float linv = 1.f / lrun;
    #pragma unroll
    for (int r = 0; r < 4; ++r) {
        float lr = __shfl(linv, l4 * 4 + r);
        int gr = q_row0 + l4 * 4 + r;
        #pragma unroll
        for (int dt = 0; dt < 4; ++dt) {
            int d = dt * 16 + l15;
            float val = o[dt][r] * lr;
            float pv = __shfl_xor(val, 1);   // partner d^1, same q
            float f = fq[(size_t)gr * DH + d];
            float sn, cs;
            sincosf(f, &sn, &cs);
            float rr = (d & 1) ? (val * cs - pv * sn) : (val * cs + pv * sn);
            unsigned short hi = f2bf(rr);
            float lo = rr - bf2f(hi);
            aobH[(size_t)gr * 512 + h * 64 + d] = hi;
            aobL[(size_t)gr * 512 + h * 64 + d] = f2bf(lo);
        }
    }
}

// ---------------------------------------------------------------------------
extern "C" void kernel_launch(void* const* d_in, const int* in_sizes, int n_in,
                              void* d_out, int out_size, void* d_ws, size_t ws_size,
                              hipStream_t stream) {
    const float* x_query   = (const float*)d_in[0];
    const float* x_context = (const float*)d_in[1];
    const float* fq        = (const float*)d_in[2];
    const float* fkv       = (const float*)d_in[3];
    const float* ln_q_g    = (const float*)d_in[4];
    const float* ln_q_b    = (const float*)d_in[5];
    const float* ln_c_g    = (const float*)d_in[6];
    const float* ln_c_b    = (const float*)d_in[7];
    const float* Wq        = (const float*)d_in[8];
    const float* Wkv       = (const float*)d_in[9];
    const float* Wout      = (const float*)d_in[10];
    const float* bout      = (const float*)d_in[11];
    float* out = (float*)d_out;

    unsigned short* xq     = (unsigned short*)d_ws;             // 8192*512
    unsigned short* xc     = xq + (size_t)NQ * 512;             // 16384*512
    unsigned short* WqT    = xc + (size_t)NKV * 512;            // 512*512
    unsigned short* WkvT   = WqT + 512 * 512;                   // 1024*512
    unsigned short* WoutTh = WkvT + 1024 * 512;                 // 512*512
    unsigned short* WoutTl = WoutTh + 512 * 512;                // 512*512
    unsigned short* qb     = WoutTl + 512 * 512;                // 8192*512
    unsigned short* kvb    = qb + (size_t)NQ * 512;             // 16384*1024
    unsigned short* aobH   = kvb + (size_t)NKV * 1024;          // 8192*512
    unsigned short* aobL   = aobH + (size_t)NQ * 512;           // 8192*512
    // vT [16384][512]^T = [128 bh][64 d][1024 k]; aliases xq+xc (dead by then)
    unsigned short* vT     = (unsigned short*)d_ws;

    ln_cast_kernel<<<NQ / 4, 256, 0, stream>>>(x_query, ln_q_g, ln_q_b, xq, NQ);
    ln_cast_kernel<<<NKV / 4, 256, 0, stream>>>(x_context, ln_c_g, ln_c_b, xc, NKV);
    wt_cast_kernel<<<512 * 512 / 256, 256, 0, stream>>>(Wq, WqT, nullptr, 512);
    wt_cast_kernel<<<1024 * 512 / 256, 256, 0, stream>>>(Wkv, WkvT, nullptr, 1024);
    wt_cast_kernel<<<512 * 512 / 256, 256, 0, stream>>>(Wout, WoutTh, WoutTl, 512);

    mm_kernel<0><<<256, 256, 0, stream>>>(
        xq, nullptr, WqT, nullptr, (void*)qb, fq, nullptr);
    mm_kernel<1><<<1024, 256, 0, stream>>>(
        xc, nullptr, WkvT, nullptr, (void*)kvb, fkv, nullptr);

    vtrans_kernel<<<2048, 256, 0, stream>>>(kvb, vT);

    attn_kernel<<<1024, 256, 0, stream>>>(qb, kvb, vT, fq, aobH, aobL);

    mm_kernel<2><<<256, 256, 0, stream>>>(
        aobH, aobL, WoutTh, WoutTl, (void*)out, nullptr, bout);
}